// Round 7
// baseline (1113.560 us; speedup 1.0000x reference)
//
#include <hip/hip_runtime.h>
#include <stdint.h>

// MultiViewHyperConvNetwork: P=200000, U=50000, NNZ=2e6, D=64, 3 layers,
// dropout 0.5 (JAX partitionable threefry), key(42) fold_in(layer).
//
// Round-5: CSR build merged for both matrices + packed (col,val) uint2
// records (one 8B random store per nnz instead of two 4B stores).
// Combined cnt/start/work arrays [U+P]; one pair array [2*nnz]; the
// combined exclusive scan places P-side segments after U-side naturally.
// SpMM: wave per row, 4 nnz/iter x2 unroll, shfl reduce (round-4 structure).

#define DIM 64
#define SCAN_BLOCK 256
#define SCAN_ITEMS 4
#define SCAN_CHUNK (SCAN_BLOCK * SCAN_ITEMS)

__host__ __device__ __forceinline__ uint32_t rotl32(uint32_t v, int d) {
    return (v << d) | (v >> (32 - d));
}

// Threefry-2x32, 20 rounds — bit-exact match to JAX's threefry2x32_p.
__host__ __device__ __forceinline__ void threefry2x32(uint32_t k0, uint32_t k1,
                                                      uint32_t& x0, uint32_t& x1) {
    const uint32_t ks0 = k0, ks1 = k1, ks2 = k0 ^ k1 ^ 0x1BD11BDAu;
    x0 += ks0; x1 += ks1;
    x0 += x1; x1 = rotl32(x1, 13); x1 ^= x0;
    x0 += x1; x1 = rotl32(x1, 15); x1 ^= x0;
    x0 += x1; x1 = rotl32(x1, 26); x1 ^= x0;
    x0 += x1; x1 = rotl32(x1, 6);  x1 ^= x0;
    x0 += ks1; x1 += ks2 + 1u;
    x0 += x1; x1 = rotl32(x1, 17); x1 ^= x0;
    x0 += x1; x1 = rotl32(x1, 29); x1 ^= x0;
    x0 += x1; x1 = rotl32(x1, 16); x1 ^= x0;
    x0 += x1; x1 = rotl32(x1, 24); x1 ^= x0;
    x0 += ks2; x1 += ks0 + 2u;
    x0 += x1; x1 = rotl32(x1, 13); x1 ^= x0;
    x0 += x1; x1 = rotl32(x1, 15); x1 ^= x0;
    x0 += x1; x1 = rotl32(x1, 26); x1 ^= x0;
    x0 += x1; x1 = rotl32(x1, 6);  x1 ^= x0;
    x0 += ks0; x1 += ks1 + 3u;
    x0 += x1; x1 = rotl32(x1, 17); x1 ^= x0;
    x0 += x1; x1 = rotl32(x1, 29); x1 ^= x0;
    x0 += x1; x1 = rotl32(x1, 16); x1 ^= x0;
    x0 += x1; x1 = rotl32(x1, 24); x1 ^= x0;
    x0 += ks1; x1 += ks2 + 4u;
    x0 += x1; x1 = rotl32(x1, 13); x1 ^= x0;
    x0 += x1; x1 = rotl32(x1, 15); x1 ^= x0;
    x0 += x1; x1 = rotl32(x1, 26); x1 ^= x0;
    x0 += x1; x1 = rotl32(x1, 6);  x1 ^= x0;
    x0 += ks2; x1 += ks0 + 5u;
}

__global__ void init_kernel(const float4* __restrict__ pois, float4* __restrict__ x,
                            float4* __restrict__ out, int n4) {
    int i = blockIdx.x * blockDim.x + threadIdx.x;
    if (i < n4) {
        float4 v = pois[i];
        x[i] = v;
        out[i] = make_float4(0.25f * v.x, 0.25f * v.y, 0.25f * v.z, 0.25f * v.w);
    }
}

// ---- merged CSR build: hist -> scan (3 kernels) -> packed scatter ----

__global__ void hist2_kernel(const int* __restrict__ up_rows, const int* __restrict__ pu_rows,
                             int* __restrict__ cnt, int U, int nnz) {
    int i = blockIdx.x * blockDim.x + threadIdx.x;
    if (i < nnz) {
        atomicAdd(&cnt[up_rows[i]], 1);
        atomicAdd(&cnt[U + pu_rows[i]], 1);
    }
}

__global__ void scan1_kernel(const int* __restrict__ cnt, int* __restrict__ start,
                             int* __restrict__ bsum, int n) {
    __shared__ int lds[SCAN_BLOCK];
    int base = blockIdx.x * SCAN_CHUNK + threadIdx.x * SCAN_ITEMS;
    int v[SCAN_ITEMS];
    int s = 0;
#pragma unroll
    for (int i = 0; i < SCAN_ITEMS; ++i) {
        int idx = base + i;
        v[i] = (idx < n) ? cnt[idx] : 0;
        s += v[i];
    }
    lds[threadIdx.x] = s;
    __syncthreads();
    for (int off = 1; off < SCAN_BLOCK; off <<= 1) {
        int t = (threadIdx.x >= off) ? lds[threadIdx.x - off] : 0;
        __syncthreads();
        lds[threadIdx.x] += t;
        __syncthreads();
    }
    if (threadIdx.x == SCAN_BLOCK - 1) bsum[blockIdx.x] = lds[SCAN_BLOCK - 1];
    int run = (threadIdx.x == 0) ? 0 : lds[threadIdx.x - 1];
#pragma unroll
    for (int i = 0; i < SCAN_ITEMS; ++i) {
        int idx = base + i;
        if (idx < n) start[idx] = run;
        run += v[i];
    }
}

__global__ void scan2_kernel(int* __restrict__ bsum, int nb) {
    __shared__ int lds[SCAN_BLOCK];
    int v = (threadIdx.x < nb) ? bsum[threadIdx.x] : 0;
    lds[threadIdx.x] = v;
    __syncthreads();
    for (int off = 1; off < SCAN_BLOCK; off <<= 1) {
        int t = (threadIdx.x >= off) ? lds[threadIdx.x - off] : 0;
        __syncthreads();
        lds[threadIdx.x] += t;
        __syncthreads();
    }
    int excl = (threadIdx.x == 0) ? 0 : lds[threadIdx.x - 1];
    if (threadIdx.x < nb) bsum[threadIdx.x] = excl;
}

__global__ void scan3_kernel(int* __restrict__ start, int* __restrict__ work,
                             const int* __restrict__ bsum, int n) {
    int off = bsum[blockIdx.x];
    int base = blockIdx.x * SCAN_CHUNK;
#pragma unroll
    for (int i = 0; i < SCAN_ITEMS; ++i) {
        int idx = base + i * SCAN_BLOCK + threadIdx.x;
        if (idx < n) {
            int s = start[idx] + off;
            start[idx] = s;
            work[idx] = s;
        }
    }
}

// Packed scatter for both matrices: one uint2 (col, val-bits) store per nnz.
// P-side destinations land at pair[>= nnz] via the combined scan offsets.
__global__ void scatter2_kernel(const int* __restrict__ up_rows, const int* __restrict__ up_cols,
                                const float* __restrict__ up_vals,
                                const int* __restrict__ pu_rows, const int* __restrict__ pu_cols,
                                const float* __restrict__ pu_vals,
                                int* __restrict__ work, uint2* __restrict__ pair,
                                int U, int nnz) {
    int i = blockIdx.x * blockDim.x + threadIdx.x;
    if (i < nnz) {
        int r0 = up_rows[i];
        int c0 = up_cols[i];
        float v0 = up_vals[i];
        int r1 = pu_rows[i];
        int c1 = pu_cols[i];
        float v1 = pu_vals[i];
        int pos0 = atomicAdd(&work[r0], 1);
        int pos1 = atomicAdd(&work[U + r1], 1);
        pair[pos0] = make_uint2((unsigned)c0, __float_as_uint(v0));
        pair[pos1] = make_uint2((unsigned)c1, __float_as_uint(v1));
    }
}

// ---- SpMM gather, high-MLP: wave per row, 4 nnz/iter x2 unroll ----
// lane = (sub = lane>>4 -> nnz slot, d4 = lane&15 -> float4 within row)

__device__ __forceinline__ float4 shfl_xor_add4(float4 a, int mask) {
    a.x += __shfl_xor(a.x, mask, 64);
    a.y += __shfl_xor(a.y, mask, 64);
    a.z += __shfl_xor(a.z, mask, 64);
    a.w += __shfl_xor(a.w, mask, 64);
    return a;
}

__device__ __forceinline__ float4 row_accumulate(const uint2* __restrict__ pair,
                                                 const float4* __restrict__ src4,
                                                 int s, int c, int sub, int d4) {
    float4 acc = make_float4(0.f, 0.f, 0.f, 0.f);
    int j = sub;
    for (; j + 4 < c; j += 8) {
        uint2 p0 = pair[s + j];
        uint2 p1 = pair[s + j + 4];
        float4 g0 = src4[(size_t)p0.x * 16 + d4];
        float4 g1 = src4[(size_t)p1.x * 16 + d4];
        float v0 = __uint_as_float(p0.y);
        float v1 = __uint_as_float(p1.y);
        acc.x += v0 * g0.x + v1 * g1.x;
        acc.y += v0 * g0.y + v1 * g1.y;
        acc.z += v0 * g0.z + v1 * g1.z;
        acc.w += v0 * g0.w + v1 * g1.w;
    }
    if (j < c) {
        uint2 p0 = pair[s + j];
        float4 g0 = src4[(size_t)p0.x * 16 + d4];
        float v0 = __uint_as_float(p0.y);
        acc.x += v0 * g0.x;
        acc.y += v0 * g0.y;
        acc.z += v0 * g0.z;
        acc.w += v0 * g0.w;
    }
    acc = shfl_xor_add4(acc, 16);
    acc = shfl_xor_add4(acc, 32);
    return acc;
}

// msg = HG_up @ x : one wave per U-row.
__global__ void spmm_gather(const int* __restrict__ start, const int* __restrict__ cnt,
                            const uint2* __restrict__ pair,
                            const float4* __restrict__ x4, float4* __restrict__ out4,
                            int nrows) {
    int wid = (blockIdx.x * blockDim.x + threadIdx.x) >> 6;
    int lane = threadIdx.x & 63;
    if (wid >= nrows) return;
    int sub = lane >> 4, d4 = lane & 15;
    float4 acc = row_accumulate(pair, x4, start[wid], cnt[wid], sub, d4);
    if (sub == 0) out4[(size_t)wid * 16 + d4] = acc;
}

// Fused P-side: prop_row = HG_pu @ msg; x = dropout(prop + x); out += x/4.
__global__ void spmm_fused(const int* __restrict__ start, const int* __restrict__ cnt,
                           const uint2* __restrict__ pair,
                           const float4* __restrict__ msg4, float* __restrict__ x,
                           float* __restrict__ out, uint32_t k0, uint32_t k1, int nrows) {
    int wid = (blockIdx.x * blockDim.x + threadIdx.x) >> 6;
    int lane = threadIdx.x & 63;
    if (wid >= nrows) return;
    int sub = lane >> 4, d4 = lane & 15;
    float4 acc = row_accumulate(pair, msg4, start[wid], cnt[wid], sub, d4);
    // redistribute: lane l takes scalar element l of the row.
    int srcl = lane >> 2;
    float a0 = __shfl(acc.x, srcl, 64);
    float a1 = __shfl(acc.y, srcl, 64);
    float a2 = __shfl(acc.z, srcl, 64);
    float a3 = __shfl(acc.w, srcl, 64);
    int comp = lane & 3;
    float av = (comp & 2) ? ((comp & 1) ? a3 : a2) : ((comp & 1) ? a1 : a0);
    size_t idx = (size_t)wid * DIM + lane;
    float a = av + x[idx];
    uint32_t hi = 0u, lo = (uint32_t)idx;   // partitionable threefry, count = flat idx
    threefry2x32(k0, k1, hi, lo);
    float nx = ((hi ^ lo) & 0x80000000u) ? 0.0f : 2.0f * a;
    x[idx] = nx;
    out[idx] += 0.25f * nx;
}

extern "C" void kernel_launch(void* const* d_in, const int* in_sizes, int n_in,
                              void* d_out, int out_size, void* d_ws, size_t ws_size,
                              hipStream_t stream) {
    const float* pois    = (const float*)d_in[0];
    const int*   up_rows = (const int*)d_in[1];
    const int*   up_cols = (const int*)d_in[2];
    const float* up_vals = (const float*)d_in[3];
    const int*   pu_rows = (const int*)d_in[4];
    const int*   pu_cols = (const int*)d_in[5];
    const float* pu_vals = (const float*)d_in[6];
    float* out = (float*)d_out;

    const int n   = in_sizes[0];           // P*DIM = 12,800,000
    const int nnz = in_sizes[1];           // 2,000,000
    const int P   = n / DIM;               // 200,000
    const int U   = 50000;                 // fixed by problem
    const int mU  = U * DIM;               // 3,200,000
    const int M   = U + P;                 // combined row count 250,000

    // workspace layout (4-byte elements; pair needs 8B alignment — holds:
    // offset of pair = (n + mU + 3M) * 4 bytes = 67,000,000, divisible by 8)
    float* x     = (float*)d_ws;                   // [n]
    float* msg   = x + n;                          // [mU]
    int*   start = (int*)(msg + mU);               // [M]  (u:0..U-1, p:U..M-1)
    int*   cnt   = start + M;                      // [M]
    int*   work  = cnt + M;                        // [M]
    uint2* pair  = (uint2*)(work + M);             // [2*nnz] (u: <nnz, p: >=nnz)
    int*   bsum  = (int*)(pair + (size_t)2 * nnz); // [<=256]

    const int n4 = n / 4;
    init_kernel<<<(n4 + 255) / 256, 256, 0, stream>>>(
        (const float4*)pois, (float4*)x, (float4*)out, n4);

    const int nzb = (nnz + 255) / 256;
    const int nb  = (M + SCAN_CHUNK - 1) / SCAN_CHUNK;   // 245 <= 256

    hipMemsetAsync(cnt, 0, (size_t)M * sizeof(int), stream);
    hist2_kernel<<<nzb, 256, 0, stream>>>(up_rows, pu_rows, cnt, U, nnz);
    scan1_kernel<<<nb, SCAN_BLOCK, 0, stream>>>(cnt, start, bsum, M);
    scan2_kernel<<<1, SCAN_BLOCK, 0, stream>>>(bsum, nb);
    scan3_kernel<<<nb, SCAN_BLOCK, 0, stream>>>(start, work, bsum, M);
    scatter2_kernel<<<nzb, 256, 0, stream>>>(up_rows, up_cols, up_vals,
                                             pu_rows, pu_cols, pu_vals,
                                             work, pair, U, nnz);

    // ---- 3 layers ----
    const long long thU = (long long)U * 64;
    const long long thP = (long long)P * 64;
    const int gU = (int)((thU + 255) / 256);
    const int gP = (int)((thP + 255) / 256);
    for (int l = 0; l < 3; ++l) {
        spmm_gather<<<gU, 256, 0, stream>>>(start, cnt, pair,
                                            (const float4*)x, (float4*)msg, U);
        uint32_t kk0 = 0u, kk1 = (uint32_t)l;
        threefry2x32(0u, 42u, kk0, kk1);   // key_l = fold_in(key(42), l)
        spmm_fused<<<gP, 256, 0, stream>>>(start + U, cnt + U, pair,
                                           (const float4*)msg, x, out, kk0, kk1, P);
    }
}

// Round 8
// 799.990 us; speedup vs baseline: 1.3920x; 1.3920x over previous
//
#include <hip/hip_runtime.h>
#include <stdint.h>

// MultiViewHyperConvNetwork: P=200000, U=50000, NNZ=2e6, D=64, 3 layers,
// dropout 0.5 (JAX partitionable threefry), key(42) fold_in(layer).
//
// Round-7: line-friendly CSR build via two-level bucket partition.
//   pass A: per-block LDS bucket histogram (bucket = row>>10, 245 buckets)
//   scan  : exclusive scan over counts[bucket][block] (131072)
//   pass B: reorder COO into bucket-sorted stage (contiguous runs/block)
//   pass C: per-bucket workgroup: LDS row-hist + LDS scan -> start/cnt
//           (replaces global hist + M-scan), then fine scatter into pair
//           within a ~130KB window (single CU => L2 merges lines).
// SpMM: wave/row, 4 nnz/iter x2 unroll, shfl reduce (unchanged).

#define DIM 64
#define SCAN_BLOCK 256
#define SCAN_ITEMS 4
#define SCAN_CHUNK (SCAN_BLOCK * SCAN_ITEMS)

#define NB_PART 512          // blocks in passes A/B
#define BSHIFT 10
#define BROWS (1 << BSHIFT)  // rows per bucket = 1024
#define NBUCKET_PAD 256      // padded bucket count (real: ceil(M/1024)=245)

__host__ __device__ __forceinline__ uint32_t rotl32(uint32_t v, int d) {
    return (v << d) | (v >> (32 - d));
}

// Threefry-2x32, 20 rounds — bit-exact match to JAX's threefry2x32_p.
__host__ __device__ __forceinline__ void threefry2x32(uint32_t k0, uint32_t k1,
                                                      uint32_t& x0, uint32_t& x1) {
    const uint32_t ks0 = k0, ks1 = k1, ks2 = k0 ^ k1 ^ 0x1BD11BDAu;
    x0 += ks0; x1 += ks1;
    x0 += x1; x1 = rotl32(x1, 13); x1 ^= x0;
    x0 += x1; x1 = rotl32(x1, 15); x1 ^= x0;
    x0 += x1; x1 = rotl32(x1, 26); x1 ^= x0;
    x0 += x1; x1 = rotl32(x1, 6);  x1 ^= x0;
    x0 += ks1; x1 += ks2 + 1u;
    x0 += x1; x1 = rotl32(x1, 17); x1 ^= x0;
    x0 += x1; x1 = rotl32(x1, 29); x1 ^= x0;
    x0 += x1; x1 = rotl32(x1, 16); x1 ^= x0;
    x0 += x1; x1 = rotl32(x1, 24); x1 ^= x0;
    x0 += ks2; x1 += ks0 + 2u;
    x0 += x1; x1 = rotl32(x1, 13); x1 ^= x0;
    x0 += x1; x1 = rotl32(x1, 15); x1 ^= x0;
    x0 += x1; x1 = rotl32(x1, 26); x1 ^= x0;
    x0 += x1; x1 = rotl32(x1, 6);  x1 ^= x0;
    x0 += ks0; x1 += ks1 + 3u;
    x0 += x1; x1 = rotl32(x1, 17); x1 ^= x0;
    x0 += x1; x1 = rotl32(x1, 29); x1 ^= x0;
    x0 += x1; x1 = rotl32(x1, 16); x1 ^= x0;
    x0 += x1; x1 = rotl32(x1, 24); x1 ^= x0;
    x0 += ks1; x1 += ks2 + 4u;
    x0 += x1; x1 = rotl32(x1, 13); x1 ^= x0;
    x0 += x1; x1 = rotl32(x1, 15); x1 ^= x0;
    x0 += x1; x1 = rotl32(x1, 26); x1 ^= x0;
    x0 += x1; x1 = rotl32(x1, 6);  x1 ^= x0;
    x0 += ks2; x1 += ks0 + 5u;
}

__global__ void init_kernel(const float4* __restrict__ pois, float4* __restrict__ x,
                            float4* __restrict__ out, int n4) {
    int i = blockIdx.x * blockDim.x + threadIdx.x;
    if (i < n4) {
        float4 v = pois[i];
        x[i] = v;
        out[i] = make_float4(0.25f * v.x, 0.25f * v.y, 0.25f * v.z, 0.25f * v.w);
    }
}

// ---- generic scan kernels (used for the counts array; also fallback) ----

__global__ void scan1_kernel(const int* __restrict__ cnt, int* __restrict__ start,
                             int* __restrict__ bsum, int n) {
    __shared__ int lds[SCAN_BLOCK];
    int base = blockIdx.x * SCAN_CHUNK + threadIdx.x * SCAN_ITEMS;
    int v[SCAN_ITEMS];
    int s = 0;
#pragma unroll
    for (int i = 0; i < SCAN_ITEMS; ++i) {
        int idx = base + i;
        v[i] = (idx < n) ? cnt[idx] : 0;
        s += v[i];
    }
    lds[threadIdx.x] = s;
    __syncthreads();
    for (int off = 1; off < SCAN_BLOCK; off <<= 1) {
        int t = (threadIdx.x >= off) ? lds[threadIdx.x - off] : 0;
        __syncthreads();
        lds[threadIdx.x] += t;
        __syncthreads();
    }
    if (threadIdx.x == SCAN_BLOCK - 1) bsum[blockIdx.x] = lds[SCAN_BLOCK - 1];
    int run = (threadIdx.x == 0) ? 0 : lds[threadIdx.x - 1];
#pragma unroll
    for (int i = 0; i < SCAN_ITEMS; ++i) {
        int idx = base + i;
        if (idx < n) start[idx] = run;
        run += v[i];
    }
}

__global__ void scan2_kernel(int* __restrict__ bsum, int nb) {
    __shared__ int lds[SCAN_BLOCK];
    int v = (threadIdx.x < nb) ? bsum[threadIdx.x] : 0;
    lds[threadIdx.x] = v;
    __syncthreads();
    for (int off = 1; off < SCAN_BLOCK; off <<= 1) {
        int t = (threadIdx.x >= off) ? lds[threadIdx.x - off] : 0;
        __syncthreads();
        lds[threadIdx.x] += t;
        __syncthreads();
    }
    int excl = (threadIdx.x == 0) ? 0 : lds[threadIdx.x - 1];
    if (threadIdx.x < nb) bsum[threadIdx.x] = excl;
}

__global__ void scan3_kernel(int* __restrict__ start, int* __restrict__ work,
                             const int* __restrict__ bsum, int n) {
    int off = bsum[blockIdx.x];
    int base = blockIdx.x * SCAN_CHUNK;
#pragma unroll
    for (int i = 0; i < SCAN_ITEMS; ++i) {
        int idx = base + i * SCAN_BLOCK + threadIdx.x;
        if (idx < n) {
            int s = start[idx] + off;
            start[idx] = s;
            work[idx] = s;
        }
    }
}

// ---- pass A: per-block bucket histogram ----
__global__ void partA_count(const int* __restrict__ up_rows, const int* __restrict__ pu_rows,
                            int* __restrict__ counts, int U, int nnz, int chunk) {
    __shared__ int h[NBUCKET_PAD];
    int blk = blockIdx.x;
    for (int t = threadIdx.x; t < NBUCKET_PAD; t += blockDim.x) h[t] = 0;
    __syncthreads();
    int s = blk * chunk, e = min(nnz, s + chunk);
    for (int i = s + (int)threadIdx.x; i < e; i += blockDim.x) {
        atomicAdd(&h[up_rows[i] >> BSHIFT], 1);
        atomicAdd(&h[(U + pu_rows[i]) >> BSHIFT], 1);
    }
    __syncthreads();
    for (int t = threadIdx.x; t < NBUCKET_PAD; t += blockDim.x)
        counts[t * NB_PART + blk] = h[t];   // bucket-major layout
}

// ---- pass B: reorder COO into bucket-sorted stage ----
// record: (rowlocal<<18 | col, val-bits); runs per (block,bucket) contiguous.
__global__ void partB_reorder(const int* __restrict__ up_rows, const int* __restrict__ up_cols,
                              const float* __restrict__ up_vals,
                              const int* __restrict__ pu_rows, const int* __restrict__ pu_cols,
                              const float* __restrict__ pu_vals,
                              const int* __restrict__ base, uint2* __restrict__ stage,
                              int U, int nnz, int chunk) {
    __shared__ int tick[NBUCKET_PAD];
    int blk = blockIdx.x;
    for (int t = threadIdx.x; t < NBUCKET_PAD; t += blockDim.x)
        tick[t] = base[t * NB_PART + blk];
    __syncthreads();
    int s = blk * chunk, e = min(nnz, s + chunk);
    for (int i = s + (int)threadIdx.x; i < e; i += blockDim.x) {
        int r0 = up_rows[i];
        unsigned c0 = (unsigned)up_cols[i];
        float v0 = up_vals[i];
        int p0 = atomicAdd(&tick[r0 >> BSHIFT], 1);
        stage[p0] = make_uint2(((unsigned)(r0 & (BROWS - 1)) << 18) | c0,
                               __float_as_uint(v0));
        int r1 = U + pu_rows[i];
        unsigned c1 = (unsigned)pu_cols[i];
        float v1 = pu_vals[i];
        int p1 = atomicAdd(&tick[r1 >> BSHIFT], 1);
        stage[p1] = make_uint2(((unsigned)(r1 & (BROWS - 1)) << 18) | c1,
                               __float_as_uint(v1));
    }
}

// ---- pass C: per-bucket row-hist + LDS scan -> start/cnt; fine scatter ----
__global__ void partC_finalize(const uint2* __restrict__ stage, const int* __restrict__ base,
                               uint2* __restrict__ pair, int* __restrict__ start,
                               int* __restrict__ cnt, int M) {
    __shared__ int h[BROWS];
    __shared__ int part[256];
    int b = blockIdx.x;
    int rowbase = b << BSHIFT;
    int bs = base[b * NB_PART];
    int be = base[(b + 1) * NB_PART];   // b+1 <= 245 < NBUCKET_PAD; padded buckets empty
    int t = threadIdx.x;
    for (int i = t; i < BROWS; i += 256) h[i] = 0;
    __syncthreads();
    for (int i = bs + t; i < be; i += 256)
        atomicAdd(&h[stage[i].x >> 18], 1);
    __syncthreads();
    // exclusive scan of h[0..1023]; thread t owns elements 4t..4t+3
    int v0 = h[4 * t], v1 = h[4 * t + 1], v2 = h[4 * t + 2], v3 = h[4 * t + 3];
    part[t] = v0 + v1 + v2 + v3;
    __syncthreads();
    for (int off = 1; off < 256; off <<= 1) {
        int u = (t >= off) ? part[t - off] : 0;
        __syncthreads();
        part[t] += u;
        __syncthreads();
    }
    int run = bs + ((t == 0) ? 0 : part[t - 1]);
    int o0 = run, o1 = run + v0, o2 = o1 + v1, o3 = o2 + v2;
    int r0 = rowbase + 4 * t;
    if (r0     < M) { start[r0]     = o0; cnt[r0]     = v0; }
    if (r0 + 1 < M) { start[r0 + 1] = o1; cnt[r0 + 1] = v1; }
    if (r0 + 2 < M) { start[r0 + 2] = o2; cnt[r0 + 2] = v2; }
    if (r0 + 3 < M) { start[r0 + 3] = o3; cnt[r0 + 3] = v3; }
    __syncthreads();
    h[4 * t] = o0; h[4 * t + 1] = o1; h[4 * t + 2] = o2; h[4 * t + 3] = o3;
    __syncthreads();
    for (int i = bs + t; i < be; i += 256) {
        uint2 rec = stage[i];
        int pos = atomicAdd(&h[rec.x >> 18], 1);
        pair[pos] = make_uint2(rec.x & 0x3FFFFu, rec.y);
    }
}

// ---- fallback (round-5) build kernels, used only if ws too small ----

__global__ void hist2_kernel(const int* __restrict__ up_rows, const int* __restrict__ pu_rows,
                             int* __restrict__ cnt, int U, int nnz) {
    int i = blockIdx.x * blockDim.x + threadIdx.x;
    if (i < nnz) {
        atomicAdd(&cnt[up_rows[i]], 1);
        atomicAdd(&cnt[U + pu_rows[i]], 1);
    }
}

__global__ void scatter2_kernel(const int* __restrict__ up_rows, const int* __restrict__ up_cols,
                                const float* __restrict__ up_vals,
                                const int* __restrict__ pu_rows, const int* __restrict__ pu_cols,
                                const float* __restrict__ pu_vals,
                                int* __restrict__ work, uint2* __restrict__ pair,
                                int U, int nnz) {
    int i = blockIdx.x * blockDim.x + threadIdx.x;
    if (i < nnz) {
        int pos0 = atomicAdd(&work[up_rows[i]], 1);
        pair[pos0] = make_uint2((unsigned)up_cols[i], __float_as_uint(up_vals[i]));
        int pos1 = atomicAdd(&work[U + pu_rows[i]], 1);
        pair[pos1] = make_uint2((unsigned)pu_cols[i], __float_as_uint(pu_vals[i]));
    }
}

// ---- SpMM gather, high-MLP: wave per row, 4 nnz/iter x2 unroll ----

__device__ __forceinline__ float4 shfl_xor_add4(float4 a, int mask) {
    a.x += __shfl_xor(a.x, mask, 64);
    a.y += __shfl_xor(a.y, mask, 64);
    a.z += __shfl_xor(a.z, mask, 64);
    a.w += __shfl_xor(a.w, mask, 64);
    return a;
}

__device__ __forceinline__ float4 row_accumulate(const uint2* __restrict__ pair,
                                                 const float4* __restrict__ src4,
                                                 int s, int c, int sub, int d4) {
    float4 acc = make_float4(0.f, 0.f, 0.f, 0.f);
    int j = sub;
    for (; j + 4 < c; j += 8) {
        uint2 p0 = pair[s + j];
        uint2 p1 = pair[s + j + 4];
        float4 g0 = src4[(size_t)p0.x * 16 + d4];
        float4 g1 = src4[(size_t)p1.x * 16 + d4];
        float v0 = __uint_as_float(p0.y);
        float v1 = __uint_as_float(p1.y);
        acc.x += v0 * g0.x + v1 * g1.x;
        acc.y += v0 * g0.y + v1 * g1.y;
        acc.z += v0 * g0.z + v1 * g1.z;
        acc.w += v0 * g0.w + v1 * g1.w;
    }
    if (j < c) {
        uint2 p0 = pair[s + j];
        float4 g0 = src4[(size_t)p0.x * 16 + d4];
        float v0 = __uint_as_float(p0.y);
        acc.x += v0 * g0.x;
        acc.y += v0 * g0.y;
        acc.z += v0 * g0.z;
        acc.w += v0 * g0.w;
    }
    acc = shfl_xor_add4(acc, 16);
    acc = shfl_xor_add4(acc, 32);
    return acc;
}

__global__ void spmm_gather(const int* __restrict__ start, const int* __restrict__ cnt,
                            const uint2* __restrict__ pair,
                            const float4* __restrict__ x4, float4* __restrict__ out4,
                            int nrows) {
    int wid = (blockIdx.x * blockDim.x + threadIdx.x) >> 6;
    int lane = threadIdx.x & 63;
    if (wid >= nrows) return;
    int sub = lane >> 4, d4 = lane & 15;
    float4 acc = row_accumulate(pair, x4, start[wid], cnt[wid], sub, d4);
    if (sub == 0) out4[(size_t)wid * 16 + d4] = acc;
}

__global__ void spmm_fused(const int* __restrict__ start, const int* __restrict__ cnt,
                           const uint2* __restrict__ pair,
                           const float4* __restrict__ msg4, float* __restrict__ x,
                           float* __restrict__ out, uint32_t k0, uint32_t k1, int nrows) {
    int wid = (blockIdx.x * blockDim.x + threadIdx.x) >> 6;
    int lane = threadIdx.x & 63;
    if (wid >= nrows) return;
    int sub = lane >> 4, d4 = lane & 15;
    float4 acc = row_accumulate(pair, msg4, start[wid], cnt[wid], sub, d4);
    int srcl = lane >> 2;
    float a0 = __shfl(acc.x, srcl, 64);
    float a1 = __shfl(acc.y, srcl, 64);
    float a2 = __shfl(acc.z, srcl, 64);
    float a3 = __shfl(acc.w, srcl, 64);
    int comp = lane & 3;
    float av = (comp & 2) ? ((comp & 1) ? a3 : a2) : ((comp & 1) ? a1 : a0);
    size_t idx = (size_t)wid * DIM + lane;
    float a = av + x[idx];
    uint32_t hi = 0u, lo = (uint32_t)idx;
    threefry2x32(k0, k1, hi, lo);
    float nx = ((hi ^ lo) & 0x80000000u) ? 0.0f : 2.0f * a;
    x[idx] = nx;
    out[idx] += 0.25f * nx;
}

extern "C" void kernel_launch(void* const* d_in, const int* in_sizes, int n_in,
                              void* d_out, int out_size, void* d_ws, size_t ws_size,
                              hipStream_t stream) {
    const float* pois    = (const float*)d_in[0];
    const int*   up_rows = (const int*)d_in[1];
    const int*   up_cols = (const int*)d_in[2];
    const float* up_vals = (const float*)d_in[3];
    const int*   pu_rows = (const int*)d_in[4];
    const int*   pu_cols = (const int*)d_in[5];
    const float* pu_vals = (const float*)d_in[6];
    float* out = (float*)d_out;

    const int n   = in_sizes[0];           // P*DIM = 12,800,000
    const int nnz = in_sizes[1];           // 2,000,000
    const int P   = n / DIM;               // 200,000
    const int U   = 50000;                 // fixed by problem
    const int mU  = U * DIM;               // 3,200,000
    const int M   = U + P;                 // 250,000
    const int NBUCKET = (M + BROWS - 1) >> BSHIFT;   // 245
    const int NT  = NBUCKET_PAD * NB_PART; // 131072 counts
    const int total2 = 2 * nnz;

    // main-path workspace layout (floats)
    float* x     = (float*)d_ws;                   // [n]
    float* msg   = x + n;                          // [mU]
    int*   start = (int*)(msg + mU);               // [M]
    int*   cnt   = start + M;                      // [M]
    int*   counts = cnt + M;                       // [NT]
    int*   basea  = counts + NT;                   // [NT]
    int*   bsum   = basea + NT;                    // [256]
    uint2* stage  = (uint2*)(bsum + 256);          // [2*nnz]
    uint2* pair   = stage + total2;                // [2*nnz]
    size_t needed = ((char*)(pair + total2)) - ((char*)d_ws);

    const int n4 = n / 4;
    init_kernel<<<(n4 + 255) / 256, 256, 0, stream>>>(
        (const float4*)pois, (float4*)x, (float4*)out, n4);

    if (needed <= ws_size) {
        // ---- radix-partition CSR build ----
        const int chunk = (nnz + NB_PART - 1) / NB_PART;   // 3907
        partA_count<<<NB_PART, 256, 0, stream>>>(up_rows, pu_rows, counts, U, nnz, chunk);
        int nb1 = (NT + SCAN_CHUNK - 1) / SCAN_CHUNK;      // 128
        scan1_kernel<<<nb1, SCAN_BLOCK, 0, stream>>>(counts, basea, bsum, NT);
        scan2_kernel<<<1, SCAN_BLOCK, 0, stream>>>(bsum, nb1);
        scan3_kernel<<<nb1, SCAN_BLOCK, 0, stream>>>(basea, basea, bsum, NT);
        partB_reorder<<<NB_PART, 256, 0, stream>>>(up_rows, up_cols, up_vals,
                                                   pu_rows, pu_cols, pu_vals,
                                                   basea, stage, U, nnz, chunk);
        partC_finalize<<<NBUCKET, 256, 0, stream>>>(stage, basea, pair, start, cnt, M);
    } else {
        // ---- fallback: round-5 path (fits in ~100MB) ----
        int* work = counts;                 // reuse [M] ints
        uint2* pairF = (uint2*)(((uintptr_t)(work + M) + 7) & ~(uintptr_t)7);
        pair = pairF;
        const int nzb = (nnz + 255) / 256;
        const int nbM = (M + SCAN_CHUNK - 1) / SCAN_CHUNK;
        hipMemsetAsync(cnt, 0, (size_t)M * sizeof(int), stream);
        hist2_kernel<<<nzb, 256, 0, stream>>>(up_rows, pu_rows, cnt, U, nnz);
        int* bsumF = (int*)(pairF + total2);
        scan1_kernel<<<nbM, SCAN_BLOCK, 0, stream>>>(cnt, start, bsumF, M);
        scan2_kernel<<<1, SCAN_BLOCK, 0, stream>>>(bsumF, nbM);
        scan3_kernel<<<nbM, SCAN_BLOCK, 0, stream>>>(start, work, bsumF, M);
        scatter2_kernel<<<nzb, 256, 0, stream>>>(up_rows, up_cols, up_vals,
                                                 pu_rows, pu_cols, pu_vals,
                                                 work, pair, U, nnz);
    }

    // ---- 3 layers ----
    const long long thU = (long long)U * 64;
    const long long thP = (long long)P * 64;
    const int gU = (int)((thU + 255) / 256);
    const int gP = (int)((thP + 255) / 256);
    for (int l = 0; l < 3; ++l) {
        spmm_gather<<<gU, 256, 0, stream>>>(start, cnt, pair,
                                            (const float4*)x, (float4*)msg, U);
        uint32_t kk0 = 0u, kk1 = (uint32_t)l;
        threefry2x32(0u, 42u, kk0, kk1);   // key_l = fold_in(key(42), l)
        spmm_fused<<<gP, 256, 0, stream>>>(start + U, cnt + U, pair,
                                           (const float4*)msg, x, out, kk0, kk1, P);
    }
}

// Round 9
// 725.412 us; speedup vs baseline: 1.5351x; 1.1028x over previous
//
#include <hip/hip_runtime.h>
#include <stdint.h>

// MultiViewHyperConvNetwork: P=200000, U=50000, NNZ=2e6, D=64, 3 layers,
// dropout 0.5 (JAX partitionable threefry), key(42) fold_in(layer).
//
// Round-8: partC at 512 threads + 2-way ILP (was 4%-occupancy bound);
// init_kernel eliminated (layer-1 reads pois directly, writes out fresh);
// layer-3 skips the dead x-store. Build pipeline otherwise unchanged:
//   partA: per-block LDS bucket hist (bucket = row>>10)
//   scan : exclusive scan over counts[bucket][block]
//   partB: reorder COO into bucket-sorted stage (contiguous runs/block)
//   partC: per-bucket row-hist + LDS scan -> start/cnt; fine scatter to pair
// SpMM: wave/row, 4 nnz/iter x2 unroll, shfl reduce.

#define DIM 64
#define SCAN_BLOCK 256
#define SCAN_ITEMS 4
#define SCAN_CHUNK (SCAN_BLOCK * SCAN_ITEMS)

#define NB_PART 512          // blocks in passes A/B
#define BSHIFT 10
#define BROWS (1 << BSHIFT)  // rows per bucket = 1024
#define NBUCKET_PAD 256      // padded bucket count (real: ceil(M/1024)=245)
#define CTHREADS 512         // partC block size

__host__ __device__ __forceinline__ uint32_t rotl32(uint32_t v, int d) {
    return (v << d) | (v >> (32 - d));
}

// Threefry-2x32, 20 rounds — bit-exact match to JAX's threefry2x32_p.
__host__ __device__ __forceinline__ void threefry2x32(uint32_t k0, uint32_t k1,
                                                      uint32_t& x0, uint32_t& x1) {
    const uint32_t ks0 = k0, ks1 = k1, ks2 = k0 ^ k1 ^ 0x1BD11BDAu;
    x0 += ks0; x1 += ks1;
    x0 += x1; x1 = rotl32(x1, 13); x1 ^= x0;
    x0 += x1; x1 = rotl32(x1, 15); x1 ^= x0;
    x0 += x1; x1 = rotl32(x1, 26); x1 ^= x0;
    x0 += x1; x1 = rotl32(x1, 6);  x1 ^= x0;
    x0 += ks1; x1 += ks2 + 1u;
    x0 += x1; x1 = rotl32(x1, 17); x1 ^= x0;
    x0 += x1; x1 = rotl32(x1, 29); x1 ^= x0;
    x0 += x1; x1 = rotl32(x1, 16); x1 ^= x0;
    x0 += x1; x1 = rotl32(x1, 24); x1 ^= x0;
    x0 += ks2; x1 += ks0 + 2u;
    x0 += x1; x1 = rotl32(x1, 13); x1 ^= x0;
    x0 += x1; x1 = rotl32(x1, 15); x1 ^= x0;
    x0 += x1; x1 = rotl32(x1, 26); x1 ^= x0;
    x0 += x1; x1 = rotl32(x1, 6);  x1 ^= x0;
    x0 += ks0; x1 += ks1 + 3u;
    x0 += x1; x1 = rotl32(x1, 17); x1 ^= x0;
    x0 += x1; x1 = rotl32(x1, 29); x1 ^= x0;
    x0 += x1; x1 = rotl32(x1, 16); x1 ^= x0;
    x0 += x1; x1 = rotl32(x1, 24); x1 ^= x0;
    x0 += ks1; x1 += ks2 + 4u;
    x0 += x1; x1 = rotl32(x1, 13); x1 ^= x0;
    x0 += x1; x1 = rotl32(x1, 15); x1 ^= x0;
    x0 += x1; x1 = rotl32(x1, 26); x1 ^= x0;
    x0 += x1; x1 = rotl32(x1, 6);  x1 ^= x0;
    x0 += ks2; x1 += ks0 + 5u;
}

// ---- generic scan kernels ----

__global__ void scan1_kernel(const int* __restrict__ cnt, int* __restrict__ start,
                             int* __restrict__ bsum, int n) {
    __shared__ int lds[SCAN_BLOCK];
    int base = blockIdx.x * SCAN_CHUNK + threadIdx.x * SCAN_ITEMS;
    int v[SCAN_ITEMS];
    int s = 0;
#pragma unroll
    for (int i = 0; i < SCAN_ITEMS; ++i) {
        int idx = base + i;
        v[i] = (idx < n) ? cnt[idx] : 0;
        s += v[i];
    }
    lds[threadIdx.x] = s;
    __syncthreads();
    for (int off = 1; off < SCAN_BLOCK; off <<= 1) {
        int t = (threadIdx.x >= off) ? lds[threadIdx.x - off] : 0;
        __syncthreads();
        lds[threadIdx.x] += t;
        __syncthreads();
    }
    if (threadIdx.x == SCAN_BLOCK - 1) bsum[blockIdx.x] = lds[SCAN_BLOCK - 1];
    int run = (threadIdx.x == 0) ? 0 : lds[threadIdx.x - 1];
#pragma unroll
    for (int i = 0; i < SCAN_ITEMS; ++i) {
        int idx = base + i;
        if (idx < n) start[idx] = run;
        run += v[i];
    }
}

__global__ void scan2_kernel(int* __restrict__ bsum, int nb) {
    __shared__ int lds[SCAN_BLOCK];
    int v = (threadIdx.x < nb) ? bsum[threadIdx.x] : 0;
    lds[threadIdx.x] = v;
    __syncthreads();
    for (int off = 1; off < SCAN_BLOCK; off <<= 1) {
        int t = (threadIdx.x >= off) ? lds[threadIdx.x - off] : 0;
        __syncthreads();
        lds[threadIdx.x] += t;
        __syncthreads();
    }
    int excl = (threadIdx.x == 0) ? 0 : lds[threadIdx.x - 1];
    if (threadIdx.x < nb) bsum[threadIdx.x] = excl;
}

__global__ void scan3_kernel(int* __restrict__ start, int* __restrict__ work,
                             const int* __restrict__ bsum, int n) {
    int off = bsum[blockIdx.x];
    int base = blockIdx.x * SCAN_CHUNK;
#pragma unroll
    for (int i = 0; i < SCAN_ITEMS; ++i) {
        int idx = base + i * SCAN_BLOCK + threadIdx.x;
        if (idx < n) {
            int s = start[idx] + off;
            start[idx] = s;
            work[idx] = s;
        }
    }
}

// ---- pass A: per-block bucket histogram ----
__global__ void partA_count(const int* __restrict__ up_rows, const int* __restrict__ pu_rows,
                            int* __restrict__ counts, int U, int nnz, int chunk) {
    __shared__ int h[NBUCKET_PAD];
    int blk = blockIdx.x;
    for (int t = threadIdx.x; t < NBUCKET_PAD; t += blockDim.x) h[t] = 0;
    __syncthreads();
    int s = blk * chunk, e = min(nnz, s + chunk);
    for (int i = s + (int)threadIdx.x; i < e; i += blockDim.x) {
        atomicAdd(&h[up_rows[i] >> BSHIFT], 1);
        atomicAdd(&h[(U + pu_rows[i]) >> BSHIFT], 1);
    }
    __syncthreads();
    for (int t = threadIdx.x; t < NBUCKET_PAD; t += blockDim.x)
        counts[t * NB_PART + blk] = h[t];   // bucket-major layout
}

// ---- pass B: reorder COO into bucket-sorted stage ----
// record: (rowlocal<<18 | col, val-bits); runs per (block,bucket) contiguous.
__global__ void partB_reorder(const int* __restrict__ up_rows, const int* __restrict__ up_cols,
                              const float* __restrict__ up_vals,
                              const int* __restrict__ pu_rows, const int* __restrict__ pu_cols,
                              const float* __restrict__ pu_vals,
                              const int* __restrict__ base, uint2* __restrict__ stage,
                              int U, int nnz, int chunk) {
    __shared__ int tick[NBUCKET_PAD];
    int blk = blockIdx.x;
    for (int t = threadIdx.x; t < NBUCKET_PAD; t += blockDim.x)
        tick[t] = base[t * NB_PART + blk];
    __syncthreads();
    int s = blk * chunk, e = min(nnz, s + chunk);
    for (int i = s + (int)threadIdx.x; i < e; i += blockDim.x) {
        int r0 = up_rows[i];
        unsigned c0 = (unsigned)up_cols[i];
        float v0 = up_vals[i];
        int p0 = atomicAdd(&tick[r0 >> BSHIFT], 1);
        stage[p0] = make_uint2(((unsigned)(r0 & (BROWS - 1)) << 18) | c0,
                               __float_as_uint(v0));
        int r1 = U + pu_rows[i];
        unsigned c1 = (unsigned)pu_cols[i];
        float v1 = pu_vals[i];
        int p1 = atomicAdd(&tick[r1 >> BSHIFT], 1);
        stage[p1] = make_uint2(((unsigned)(r1 & (BROWS - 1)) << 18) | c1,
                               __float_as_uint(v1));
    }
}

// ---- pass C: per-bucket row-hist + LDS scan -> start/cnt; fine scatter ----
// 512 threads, 2-way ILP in both sweeps.
__global__ void partC_finalize(const uint2* __restrict__ stage, const int* __restrict__ base,
                               uint2* __restrict__ pair, int* __restrict__ start,
                               int* __restrict__ cnt, int M) {
    __shared__ int h[BROWS];
    __shared__ int part[CTHREADS];
    int b = blockIdx.x;
    int rowbase = b << BSHIFT;
    int bs = base[b * NB_PART];
    int be = base[(b + 1) * NB_PART];   // padded buckets beyond real count are empty
    int t = threadIdx.x;
    h[t] = 0;
    h[t + CTHREADS] = 0;
    __syncthreads();
    for (int i = bs + t; i < be; i += 2 * CTHREADS) {
        uint32_t a0 = stage[i].x;
        int i1 = i + CTHREADS;
        bool has1 = i1 < be;
        uint32_t a1 = has1 ? stage[i1].x : 0u;
        atomicAdd(&h[a0 >> 18], 1);
        if (has1) atomicAdd(&h[a1 >> 18], 1);
    }
    __syncthreads();
    // exclusive scan of h[0..1023]; thread t owns elements 2t, 2t+1
    int v0 = h[2 * t], v1 = h[2 * t + 1];
    part[t] = v0 + v1;
    __syncthreads();
    for (int off = 1; off < CTHREADS; off <<= 1) {
        int u = (t >= off) ? part[t - off] : 0;
        __syncthreads();
        part[t] += u;
        __syncthreads();
    }
    int run = bs + ((t == 0) ? 0 : part[t - 1]);
    int o0 = run, o1 = run + v0;
    int r0 = rowbase + 2 * t;
    if (r0     < M) { start[r0]     = o0; cnt[r0]     = v0; }
    if (r0 + 1 < M) { start[r0 + 1] = o1; cnt[r0 + 1] = v1; }
    __syncthreads();
    h[2 * t] = o0; h[2 * t + 1] = o1;
    __syncthreads();
    for (int i = bs + t; i < be; i += 2 * CTHREADS) {
        uint2 rec0 = stage[i];
        int i1 = i + CTHREADS;
        bool has1 = i1 < be;
        uint2 rec1 = has1 ? stage[i1] : make_uint2(0u, 0u);
        int p0 = atomicAdd(&h[rec0.x >> 18], 1);
        pair[p0] = make_uint2(rec0.x & 0x3FFFFu, rec0.y);
        if (has1) {
            int p1 = atomicAdd(&h[rec1.x >> 18], 1);
            pair[p1] = make_uint2(rec1.x & 0x3FFFFu, rec1.y);
        }
    }
}

// ---- fallback (round-5) build kernels, used only if ws too small ----

__global__ void hist2_kernel(const int* __restrict__ up_rows, const int* __restrict__ pu_rows,
                             int* __restrict__ cnt, int U, int nnz) {
    int i = blockIdx.x * blockDim.x + threadIdx.x;
    if (i < nnz) {
        atomicAdd(&cnt[up_rows[i]], 1);
        atomicAdd(&cnt[U + pu_rows[i]], 1);
    }
}

__global__ void scatter2_kernel(const int* __restrict__ up_rows, const int* __restrict__ up_cols,
                                const float* __restrict__ up_vals,
                                const int* __restrict__ pu_rows, const int* __restrict__ pu_cols,
                                const float* __restrict__ pu_vals,
                                int* __restrict__ work, uint2* __restrict__ pair,
                                int U, int nnz) {
    int i = blockIdx.x * blockDim.x + threadIdx.x;
    if (i < nnz) {
        int pos0 = atomicAdd(&work[up_rows[i]], 1);
        pair[pos0] = make_uint2((unsigned)up_cols[i], __float_as_uint(up_vals[i]));
        int pos1 = atomicAdd(&work[U + pu_rows[i]], 1);
        pair[pos1] = make_uint2((unsigned)pu_cols[i], __float_as_uint(pu_vals[i]));
    }
}

// ---- SpMM gather, high-MLP: wave per row, 4 nnz/iter x2 unroll ----

__device__ __forceinline__ float4 shfl_xor_add4(float4 a, int mask) {
    a.x += __shfl_xor(a.x, mask, 64);
    a.y += __shfl_xor(a.y, mask, 64);
    a.z += __shfl_xor(a.z, mask, 64);
    a.w += __shfl_xor(a.w, mask, 64);
    return a;
}

__device__ __forceinline__ float4 row_accumulate(const uint2* __restrict__ pair,
                                                 const float4* __restrict__ src4,
                                                 int s, int c, int sub, int d4) {
    float4 acc = make_float4(0.f, 0.f, 0.f, 0.f);
    int j = sub;
    for (; j + 4 < c; j += 8) {
        uint2 p0 = pair[s + j];
        uint2 p1 = pair[s + j + 4];
        float4 g0 = src4[(size_t)p0.x * 16 + d4];
        float4 g1 = src4[(size_t)p1.x * 16 + d4];
        float v0 = __uint_as_float(p0.y);
        float v1 = __uint_as_float(p1.y);
        acc.x += v0 * g0.x + v1 * g1.x;
        acc.y += v0 * g0.y + v1 * g1.y;
        acc.z += v0 * g0.z + v1 * g1.z;
        acc.w += v0 * g0.w + v1 * g1.w;
    }
    if (j < c) {
        uint2 p0 = pair[s + j];
        float4 g0 = src4[(size_t)p0.x * 16 + d4];
        float v0 = __uint_as_float(p0.y);
        acc.x += v0 * g0.x;
        acc.y += v0 * g0.y;
        acc.z += v0 * g0.z;
        acc.w += v0 * g0.w;
    }
    acc = shfl_xor_add4(acc, 16);
    acc = shfl_xor_add4(acc, 32);
    return acc;
}

__global__ void spmm_gather(const int* __restrict__ start, const int* __restrict__ cnt,
                            const uint2* __restrict__ pair,
                            const float4* __restrict__ x4, float4* __restrict__ out4,
                            int nrows) {
    int wid = (blockIdx.x * blockDim.x + threadIdx.x) >> 6;
    int lane = threadIdx.x & 63;
    if (wid >= nrows) return;
    int sub = lane >> 4, d4 = lane & 15;
    float4 acc = row_accumulate(pair, x4, start[wid], cnt[wid], sub, d4);
    if (sub == 0) out4[(size_t)wid * 16 + d4] = acc;
}

// Fused P-side: prop_row = HG_pu @ msg; x_new = dropout(prop + x_res);
// FIRST: out = 0.25*(x_res + x_new)  (x_res = pois)   — overwrites poison.
// else : out += 0.25*x_new.
// LAST : skip x_new store (dead after final out update).
template <bool FIRST, bool LAST>
__global__ void spmm_fused_t(const int* __restrict__ start, const int* __restrict__ cnt,
                             const uint2* __restrict__ pair,
                             const float4* __restrict__ msg4,
                             const float* __restrict__ xres, float* __restrict__ xout,
                             float* __restrict__ out, uint32_t k0, uint32_t k1, int nrows) {
    int wid = (blockIdx.x * blockDim.x + threadIdx.x) >> 6;
    int lane = threadIdx.x & 63;
    if (wid >= nrows) return;
    int sub = lane >> 4, d4 = lane & 15;
    float4 acc = row_accumulate(pair, msg4, start[wid], cnt[wid], sub, d4);
    int srcl = lane >> 2;
    float a0 = __shfl(acc.x, srcl, 64);
    float a1 = __shfl(acc.y, srcl, 64);
    float a2 = __shfl(acc.z, srcl, 64);
    float a3 = __shfl(acc.w, srcl, 64);
    int comp = lane & 3;
    float av = (comp & 2) ? ((comp & 1) ? a3 : a2) : ((comp & 1) ? a1 : a0);
    size_t idx = (size_t)wid * DIM + lane;
    float xv = xres[idx];
    float a = av + xv;
    uint32_t hi = 0u, lo = (uint32_t)idx;   // partitionable threefry, count = flat idx
    threefry2x32(k0, k1, hi, lo);
    float nx = ((hi ^ lo) & 0x80000000u) ? 0.0f : 2.0f * a;
    if (!LAST) xout[idx] = nx;
    if (FIRST) out[idx] = 0.25f * (xv + nx);
    else       out[idx] += 0.25f * nx;
}

extern "C" void kernel_launch(void* const* d_in, const int* in_sizes, int n_in,
                              void* d_out, int out_size, void* d_ws, size_t ws_size,
                              hipStream_t stream) {
    const float* pois    = (const float*)d_in[0];
    const int*   up_rows = (const int*)d_in[1];
    const int*   up_cols = (const int*)d_in[2];
    const float* up_vals = (const float*)d_in[3];
    const int*   pu_rows = (const int*)d_in[4];
    const int*   pu_cols = (const int*)d_in[5];
    const float* pu_vals = (const float*)d_in[6];
    float* out = (float*)d_out;

    const int n   = in_sizes[0];           // P*DIM = 12,800,000
    const int nnz = in_sizes[1];           // 2,000,000
    const int P   = n / DIM;               // 200,000
    const int U   = 50000;                 // fixed by problem
    const int mU  = U * DIM;               // 3,200,000
    const int M   = U + P;                 // 250,000
    const int NBUCKET = (M + BROWS - 1) >> BSHIFT;   // 245
    const int NT  = NBUCKET_PAD * NB_PART; // 131072 counts
    const int total2 = 2 * nnz;

    // main-path workspace layout (floats)
    float* x      = (float*)d_ws;                  // [n]
    float* msg    = x + n;                         // [mU]
    int*   start  = (int*)(msg + mU);              // [M]
    int*   cnt    = start + M;                     // [M]
    int*   counts = cnt + M;                       // [NT]
    int*   basea  = counts + NT;                   // [NT]
    int*   bsum   = basea + NT;                    // [256]
    uint2* stage  = (uint2*)(bsum + 256);          // [2*nnz]
    uint2* pair   = stage + total2;                // [2*nnz]
    size_t needed = ((char*)(pair + total2)) - ((char*)d_ws);

    if (needed <= ws_size) {
        // ---- radix-partition CSR build ----
        const int chunk = (nnz + NB_PART - 1) / NB_PART;   // 3907
        partA_count<<<NB_PART, 256, 0, stream>>>(up_rows, pu_rows, counts, U, nnz, chunk);
        int nb1 = (NT + SCAN_CHUNK - 1) / SCAN_CHUNK;      // 128
        scan1_kernel<<<nb1, SCAN_BLOCK, 0, stream>>>(counts, basea, bsum, NT);
        scan2_kernel<<<1, SCAN_BLOCK, 0, stream>>>(bsum, nb1);
        scan3_kernel<<<nb1, SCAN_BLOCK, 0, stream>>>(basea, basea, bsum, NT);
        partB_reorder<<<NB_PART, 256, 0, stream>>>(up_rows, up_cols, up_vals,
                                                   pu_rows, pu_cols, pu_vals,
                                                   basea, stage, U, nnz, chunk);
        partC_finalize<<<NBUCKET, CTHREADS, 0, stream>>>(stage, basea, pair, start, cnt, M);
    } else {
        // ---- fallback: round-5 path ----
        int* work = counts;                 // reuse [M] ints
        uint2* pairF = (uint2*)(((uintptr_t)(work + M) + 7) & ~(uintptr_t)7);
        pair = pairF;
        const int nzb = (nnz + 255) / 256;
        const int nbM = (M + SCAN_CHUNK - 1) / SCAN_CHUNK;
        hipMemsetAsync(cnt, 0, (size_t)M * sizeof(int), stream);
        hist2_kernel<<<nzb, 256, 0, stream>>>(up_rows, pu_rows, cnt, U, nnz);
        int* bsumF = (int*)(pairF + total2);
        scan1_kernel<<<nbM, SCAN_BLOCK, 0, stream>>>(cnt, start, bsumF, M);
        scan2_kernel<<<1, SCAN_BLOCK, 0, stream>>>(bsumF, nbM);
        scan3_kernel<<<nbM, SCAN_BLOCK, 0, stream>>>(start, work, bsumF, M);
        scatter2_kernel<<<nzb, 256, 0, stream>>>(up_rows, up_cols, up_vals,
                                                 pu_rows, pu_cols, pu_vals,
                                                 work, pair, U, nnz);
    }

    // ---- 3 layers (layer 1 reads pois directly; no init kernel) ----
    const long long thU = (long long)U * 64;
    const long long thP = (long long)P * 64;
    const int gU = (int)((thU + 255) / 256);
    const int gP = (int)((thP + 255) / 256);

    uint32_t key0[3], key1[3];
    for (int l = 0; l < 3; ++l) {
        uint32_t kk0 = 0u, kk1 = (uint32_t)l;
        threefry2x32(0u, 42u, kk0, kk1);   // key_l = fold_in(key(42), l)
        key0[l] = kk0; key1[l] = kk1;
    }

    // layer 1: src = pois, residual = pois, out = fresh write
    spmm_gather<<<gU, 256, 0, stream>>>(start, cnt, pair,
                                        (const float4*)pois, (float4*)msg, U);
    spmm_fused_t<true, false><<<gP, 256, 0, stream>>>(start + U, cnt + U, pair,
                                                      (const float4*)msg, pois, x,
                                                      out, key0[0], key1[0], P);
    // layer 2
    spmm_gather<<<gU, 256, 0, stream>>>(start, cnt, pair,
                                        (const float4*)x, (float4*)msg, U);
    spmm_fused_t<false, false><<<gP, 256, 0, stream>>>(start + U, cnt + U, pair,
                                                       (const float4*)msg, x, x,
                                                       out, key0[1], key1[1], P);
    // layer 3: x-store dead, skip it
    spmm_gather<<<gU, 256, 0, stream>>>(start, cnt, pair,
                                        (const float4*)x, (float4*)msg, U);
    spmm_fused_t<false, true><<<gP, 256, 0, stream>>>(start + U, cnt + U, pair,
                                                      (const float4*)msg, x, x,
                                                      out, key0[2], key1[2], P);
}